// Round 4
// baseline (211.422 us; speedup 1.0000x reference)
//
#include <hip/hip_runtime.h>

// GraphSAGE layer, fp32, N=50000 nodes, E=800000 edges, 64->64.
// Pipeline: memset -> hist -> scan(reduce/partials/write) -> XCD-local CSR fill
//           -> gather-mean aggregation (readlane-broadcast) -> GEMM via LDS tile.

#define N_NODES 50000
#define N_EDGES 800000
#define DIM 64
#define NB_SCAN 49            // 49 blocks * 1024 = 50176 >= N_NODES
#define CNT_PAD (NB_SCAN * 1024)
#define FILL_CHUNK 2048
#define FILL_NCHUNK ((N_EDGES + FILL_CHUNK - 1) / FILL_CHUNK)   // 391
#define NODES_PER_XCD (N_NODES / 8)                              // 6250

// ---------------------------------------------------------------------------
// 1) degree histogram (int atomics)
// ---------------------------------------------------------------------------
__global__ __launch_bounds__(256) void sage_hist(const int* __restrict__ src,
                                                 int* __restrict__ cnt)
{
    int e = blockIdx.x * 256 + threadIdx.x;
    if (e < N_EDGES) atomicAdd(&cnt[src[e]], 1);
}

// ---------------------------------------------------------------------------
// 2a) per-1024-chunk reduction
// ---------------------------------------------------------------------------
__global__ __launch_bounds__(256) void scan_reduce(const int* __restrict__ cnt,
                                                   int* __restrict__ partial)
{
    __shared__ int sdata[256];
    int t = threadIdx.x, b = blockIdx.x;
    int s = 0;
#pragma unroll
    for (int i = 0; i < 4; ++i) s += cnt[b * 1024 + i * 256 + t];
    sdata[t] = s; __syncthreads();
    for (int st = 128; st > 0; st >>= 1) {
        if (t < st) sdata[t] += sdata[t + st];
        __syncthreads();
    }
    if (t == 0) partial[b] = sdata[0];
}

// 2b) exclusive scan of the 49 chunk sums (single wave)
__global__ void scan_partials(int* partial)
{
    int t = threadIdx.x;
    int orig = (t < NB_SCAN) ? partial[t] : 0;
    int v = orig;
#pragma unroll
    for (int off = 1; off < 64; off <<= 1) {
        int u = __shfl_up(v, off);
        if (t >= off) v += u;
    }
    if (t < NB_SCAN) partial[t] = v - orig;
}

// 2c) per-chunk exclusive scan + chunk prefix -> row offsets + cursor copy
__global__ __launch_bounds__(256) void scan_write(const int* __restrict__ cnt,
                                                  const int* __restrict__ partial,
                                                  int* __restrict__ offs,
                                                  int* __restrict__ cursor)
{
    int t = threadIdx.x, b = blockIdx.x;
    int base = b * 1024 + t * 4;
    const int4 c = *reinterpret_cast<const int4*>(cnt + base);
    int tsum = c.x + c.y + c.z + c.w;
    int lane = t & 63, w = t >> 6;
    int v = tsum;
#pragma unroll
    for (int off = 1; off < 64; off <<= 1) {
        int u = __shfl_up(v, off);
        if (lane >= off) v += u;
    }
    __shared__ int wsum[4];
    if (lane == 63) wsum[w] = v;
    __syncthreads();
    int woff = 0;
    for (int k = 0; k < w; ++k) woff += wsum[k];
    int excl = partial[b] + woff + (v - tsum);
    int4 o; o.x = excl; o.y = o.x + c.x; o.z = o.y + c.y; o.w = o.z + c.z;
    *reinterpret_cast<int4*>(offs + base) = o;
    *reinterpret_cast<int4*>(cursor + base) = o;
}

// ---------------------------------------------------------------------------
// 3) CSR fill, XCD-partitioned: each XCD's blocks scan all edges (via a
//    per-XCD work-stealing chunk counter) and process only edges whose src
//    lies in the XCD's node range. All col writes to a given 64B line then
//    come from ONE (non-coherent) L2 -> full-line writebacks, no 16x
//    write amplification.
// ---------------------------------------------------------------------------
__global__ __launch_bounds__(256) void sage_fill(const int* __restrict__ src,
                                                 const int* __restrict__ dst,
                                                 int* __restrict__ cursor,
                                                 int* __restrict__ col,
                                                 int* __restrict__ xcdctr)
{
    unsigned int xcd;
    asm volatile("s_getreg_b32 %0, hwreg(HW_REG_XCC_ID)" : "=s"(xcd));
    xcd &= 7;
    const int lo = (int)xcd * NODES_PER_XCD;
    const int hi = lo + NODES_PER_XCD;   // 8*6250 == 50000 exactly
    const int t = threadIdx.x;

    for (;;) {
        int c;
        if (t == 0) c = atomicAdd(&xcdctr[xcd], 1);
        c = __shfl(c, 0);                       // broadcast within wave...
        __shared__ int csh;                     // ...and across the block
        if (t == 0) csh = c;
        __syncthreads();
        c = csh;
        __syncthreads();
        if (c >= FILL_NCHUNK) break;
        int base = c * FILL_CHUNK;
#pragma unroll
        for (int i = 0; i < FILL_CHUNK / 256; ++i) {
            int e = base + i * 256 + t;
            if (e < N_EDGES) {
                int s = src[e];
                if (s >= lo && s < hi) {
                    int pos = atomicAdd(&cursor[s], 1);
                    col[pos] = dst[e];
                }
            }
        }
    }
}

// ---------------------------------------------------------------------------
// 4) gather-mean: one wave per node. Neighbor indices for a 64-batch are
//    fetched with a single coalesced lane-load, then broadcast via
//    v_readlane -> 8 independent row-gathers in flight, no dependent
//    col-load chain.
// ---------------------------------------------------------------------------
__global__ __launch_bounds__(256) void sage_agg(const float* __restrict__ x,
                                                const int* __restrict__ col,
                                                const int* __restrict__ offs,
                                                float* __restrict__ agg)
{
    int wid = (blockIdx.x * 256 + threadIdx.x) >> 6;   // == node, grid sized exactly
    int lane = threadIdx.x & 63;
    int beg = offs[wid];
    int end = offs[wid + 1];
    int nb = end - beg;
    float s = 0.0f;
    for (int base = 0; base < nb; base += 64) {
        int m = nb - base; if (m > 64) m = 64;
        int li = lane < m ? lane : 0;
        int cv = col[beg + base + li];
        int j = 0;
        for (; j + 8 <= m; j += 8) {
            int d0 = __builtin_amdgcn_readlane(cv, j + 0);
            int d1 = __builtin_amdgcn_readlane(cv, j + 1);
            int d2 = __builtin_amdgcn_readlane(cv, j + 2);
            int d3 = __builtin_amdgcn_readlane(cv, j + 3);
            int d4 = __builtin_amdgcn_readlane(cv, j + 4);
            int d5 = __builtin_amdgcn_readlane(cv, j + 5);
            int d6 = __builtin_amdgcn_readlane(cv, j + 6);
            int d7 = __builtin_amdgcn_readlane(cv, j + 7);
            float t0 = x[d0 * DIM + lane] + x[d1 * DIM + lane];
            float t1 = x[d2 * DIM + lane] + x[d3 * DIM + lane];
            float t2 = x[d4 * DIM + lane] + x[d5 * DIM + lane];
            float t3 = x[d6 * DIM + lane] + x[d7 * DIM + lane];
            s += (t0 + t1) + (t2 + t3);
        }
        for (; j < m; ++j) {
            int d = __builtin_amdgcn_readlane(cv, j);
            s += x[d * DIM + lane];
        }
    }
    float inv = 1.0f / (float)(nb > 0 ? nb : 1);
    agg[(size_t)wid * DIM + lane] = s * inv;
}

// ---------------------------------------------------------------------------
// 5) fused dual GEMM + bias + relu.
//    Block = 256 threads = 4 waves; block owns 64 nodes; wave og owns 16
//    output dims (wave-uniform -> all weight/bias reads are scalar loads).
//    x/agg rows staged through LDS: coalesced float4 global reads, XOR
//    swizzle (unit c ^ (row&7)) so the per-row ds_read_b128 stream sits at
//    the LDS bandwidth floor (no conflicts).
// ---------------------------------------------------------------------------
__global__ __launch_bounds__(256) void sage_out(const float* __restrict__ x,
                                                const float* __restrict__ agg,
                                                const float* __restrict__ Ws,
                                                const float* __restrict__ bs,
                                                const float* __restrict__ Wn,
                                                const float* __restrict__ bn,
                                                float* __restrict__ out)
{
    __shared__ float xs[64 * 64];
    __shared__ float as[64 * 64];
    const int t = threadIdx.x;
    const int nbase = blockIdx.x * 64;

    const float4* __restrict__ x4 = reinterpret_cast<const float4*>(x);
    const float4* __restrict__ a4 = reinterpret_cast<const float4*>(agg);
    const float4 zero4 = make_float4(0.f, 0.f, 0.f, 0.f);

#pragma unroll
    for (int i = 0; i < 4; ++i) {
        int f = t + i * 256;            // linear float4 index 0..1023
        int r = f >> 4;                 // row (node within tile)
        int c = f & 15;                 // 16B unit within row
        int n = nbase + r;
        int p = (r * 16 + (c ^ (r & 7))) * 4;
        float4 xv = (n < N_NODES) ? x4[(size_t)n * 16 + c] : zero4;
        float4 av = (n < N_NODES) ? a4[(size_t)n * 16 + c] : zero4;
        *reinterpret_cast<float4*>(xs + p) = xv;
        *reinterpret_cast<float4*>(as + p) = av;
    }
    __syncthreads();

    const int lane = t & 63;            // node row within tile
    const int og = t >> 6;              // wave-uniform output group 0..3
    const int obase = og * 16;
    const int node = nbase + lane;

    float acc[16];
#pragma unroll
    for (int o = 0; o < 16; ++o) acc[o] = bs[obase + o] + bn[obase + o];

#pragma unroll 4
    for (int c = 0; c < 16; ++c) {
        int p = (lane * 16 + (c ^ (lane & 7))) * 4;
        float4 xv = *reinterpret_cast<const float4*>(xs + p);
        float4 av = *reinterpret_cast<const float4*>(as + p);
        int k = c * 4;
#pragma unroll
        for (int o = 0; o < 16; ++o) {
            const float* wsp = Ws + (size_t)(obase + o) * DIM + k;
            const float* wnp = Wn + (size_t)(obase + o) * DIM + k;
            float a = acc[o];
            a = fmaf(xv.x, wsp[0], a);
            a = fmaf(xv.y, wsp[1], a);
            a = fmaf(xv.z, wsp[2], a);
            a = fmaf(xv.w, wsp[3], a);
            a = fmaf(av.x, wnp[0], a);
            a = fmaf(av.y, wnp[1], a);
            a = fmaf(av.z, wnp[2], a);
            a = fmaf(av.w, wnp[3], a);
            acc[o] = a;
        }
    }

    if (node < N_NODES) {
#pragma unroll
        for (int i = 0; i < 4; ++i) {
            float4 r;
            r.x = fmaxf(acc[i * 4 + 0], 0.0f);
            r.y = fmaxf(acc[i * 4 + 1], 0.0f);
            r.z = fmaxf(acc[i * 4 + 2], 0.0f);
            r.w = fmaxf(acc[i * 4 + 3], 0.0f);
            *reinterpret_cast<float4*>(out + (size_t)node * DIM + obase + i * 4) = r;
        }
    }
}

extern "C" void kernel_launch(void* const* d_in, const int* in_sizes, int n_in,
                              void* d_out, int out_size, void* d_ws, size_t ws_size,
                              hipStream_t stream)
{
    const float* x      = (const float*)d_in[0];
    const int*   ei     = (const int*)d_in[1];   // [2,E]: row 0 = src, row 1 = dst
    const float* Wself  = (const float*)d_in[2];
    const float* bself  = (const float*)d_in[3];
    const float* Wneigh = (const float*)d_in[4];
    const float* bneigh = (const float*)d_in[5];
    float* out = (float*)d_out;

    // workspace layout (4-byte units)
    float* agg   = (float*)d_ws;                        // 3,200,000
    int* col     = (int*)(agg + (size_t)N_NODES * DIM); // 800,000
    int* cnt     = col + N_EDGES;                       // CNT_PAD
    int* xcdctr  = cnt + CNT_PAD;                       // 16
    int* offs    = xcdctr + 16;                         // CNT_PAD
    int* cursor  = offs + CNT_PAD;                      // CNT_PAD
    int* partial = cursor + CNT_PAD;                    // 64

    const int* src = ei;
    const int* dst = ei + N_EDGES;

    hipMemsetAsync(cnt, 0, (CNT_PAD + 16) * sizeof(int), stream);

    sage_hist    <<<(N_EDGES + 255) / 256, 256, 0, stream>>>(src, cnt);
    scan_reduce  <<<NB_SCAN, 256, 0, stream>>>(cnt, partial);
    scan_partials<<<1, 64, 0, stream>>>(partial);
    scan_write   <<<NB_SCAN, 256, 0, stream>>>(cnt, partial, offs, cursor);
    sage_fill    <<<1024, 256, 0, stream>>>(src, dst, cursor, col, xcdctr);

    sage_agg <<<N_NODES / 4, 256, 0, stream>>>(x, col, offs, agg);   // 12500 blocks, 50000 waves
    sage_out <<<(N_NODES + 63) / 64, 256, 0, stream>>>(x, agg, Wself, bself,
                                                       Wneigh, bneigh, out);
}